// Round 1
// baseline (602.613 us; speedup 1.0000x reference)
//
#include <hip/hip_runtime.h>
#include <math.h>

#define B_N 64
#define T_N 256
#define E_N 64
#define R_N 4
#define S_N 8

// adj[i,j] = dot(X[i,:], X[j,:]) / T ; X: [64, L]. One wave per (i,j) pair.
__global__ void gram_kernel(const float* __restrict__ X, float* __restrict__ adj, int L) {
    int wave = (blockIdx.x * blockDim.x + threadIdx.x) >> 6;
    int lane = threadIdx.x & 63;
    int i = wave >> 6;
    int j = wave & 63;
    const float* xi = X + (size_t)i * L;
    const float* xj = X + (size_t)j * L;
    float acc = 0.f;
    for (int k = lane; k < L; k += 64) acc += xi[k] * xj[k];
    for (int m = 32; m >= 1; m >>= 1) acc += __shfl_xor(acc, m, 64);
    if (lane == 0) adj[i * 64 + j] = acc * (1.0f / (float)T_N);
}

// Row-wise sparsemax on a [64,64] matrix, in place. One thread per row.
// Replicates reference exactly: sort desc, cumsum, count support, tau.
__global__ void sparsemax_kernel(float* adj) {
    int row = threadIdx.x;
    if (row >= 64) return;
    float z[64], zs[64], zcum[64];
    for (int i = 0; i < 64; i++) { z[i] = adj[row * 64 + i]; zs[i] = z[i]; }
    // insertion sort, descending
    for (int i = 1; i < 64; i++) {
        float key = zs[i];
        int j = i - 1;
        while (j >= 0 && zs[j] < key) { zs[j + 1] = zs[j]; j--; }
        zs[j + 1] = key;
    }
    float c = 0.f;
    for (int k = 0; k < 64; k++) { c += zs[k]; zcum[k] = c; }
    int ksel = 0;
    for (int k = 1; k <= 64; k++)
        if (1.0f + (float)k * zs[k - 1] > zcum[k - 1]) ksel++;
    float tau = (zcum[ksel - 1] - 1.0f) / (float)ksel;
    for (int i = 0; i < 64; i++) adj[row * 64 + i] = fmaxf(z[i] - tau, 0.f);
}

// Layer-0: agg[B,t,e] = sum_b max_{b' in [b-1,b+2]} adj[B,b']*x[b',t,e]
// then h0[B,t,r] = relu(sum_e agg * W0[e,r]). One wave per (B,t); lane = e.
__global__ void agg0_kernel(const float* __restrict__ x, const float* __restrict__ adj,
                            const float* __restrict__ W0, float* __restrict__ h0) {
    int wave = (blockIdx.x * blockDim.x + threadIdx.x) >> 6;
    int lane = threadIdx.x & 63;
    int Bi = wave >> 8;        // / 256
    int t  = wave & 255;
    float p = adj[Bi * 64 + lane];              // lane holds adj[Bi, lane]
    const float* xb = x + (size_t)t * E_N + lane;   // x[(b*T + t)*E + lane]
    const size_t bs = (size_t)T_N * E_N;
    // sliding window over b: window for output b = {b-1, b, b+1, b+2}, -inf pad
    float vm1 = -INFINITY;
    float v0 = __shfl(p, 0) * xb[0];
    float v1 = __shfl(p, 1) * xb[bs];
    float acc = 0.f;
    for (int b = 0; b < 64; b++) {
        float v2 = (b + 2 < 64) ? __shfl(p, b + 2) * xb[(size_t)(b + 2) * bs] : -INFINITY;
        acc += fmaxf(fmaxf(vm1, v0), fmaxf(v1, v2));
        vm1 = v0; v0 = v1; v1 = v2;
    }
    // GEMM E->4 + relu via 4 butterfly reductions
    const float* wrow = W0 + lane * R_N;
    float p0 = acc * wrow[0], p1 = acc * wrow[1], p2 = acc * wrow[2], p3 = acc * wrow[3];
    for (int m = 32; m >= 1; m >>= 1) {
        p0 += __shfl_xor(p0, m, 64);
        p1 += __shfl_xor(p1, m, 64);
        p2 += __shfl_xor(p2, m, 64);
        p3 += __shfl_xor(p3, m, 64);
    }
    if (lane == 0) {
        float* o = h0 + ((size_t)Bi * T_N + t) * R_N;
        o[0] = fmaxf(p0, 0.f); o[1] = fmaxf(p1, 0.f);
        o[2] = fmaxf(p2, 0.f); o[3] = fmaxf(p3, 0.f);
    }
}

// Layer-1: same aggregation on h0 [64,256,4], then 4x4 GEMM + relu.
// One wave handles (B, 16 t's); lane = tl*4 + r (coalesced along flat [t,r]).
__global__ void agg1_kernel(const float* __restrict__ h0, const float* __restrict__ adj,
                            const float* __restrict__ W1, float* __restrict__ h1) {
    int wave = (blockIdx.x * blockDim.x + threadIdx.x) >> 6;
    int lane = threadIdx.x & 63;
    int Bi = wave >> 4;            // 64 B's
    int tb = (wave & 15) * 16;     // 16 t's per wave
    float p = adj[Bi * 64 + lane];
    const float* xb = h0 + (size_t)tb * R_N + lane;  // h0[(b*T + tb)*4 + lane]
    const size_t bs = (size_t)T_N * R_N;
    float vm1 = -INFINITY;
    float v0 = __shfl(p, 0) * xb[0];
    float v1 = __shfl(p, 1) * xb[bs];
    float acc = 0.f;
    for (int b = 0; b < 64; b++) {
        float v2 = (b + 2 < 64) ? __shfl(p, b + 2) * xb[(size_t)(b + 2) * bs] : -INFINITY;
        acc += fmaxf(fmaxf(vm1, v0), fmaxf(v1, v2));
        vm1 = v0; v0 = v1; v1 = v2;
    }
    // 4x4 GEMM within each quad of lanes
    int base = lane & ~3;
    int rc = lane & 3;
    float a0 = __shfl(acc, base + 0);
    float a1 = __shfl(acc, base + 1);
    float a2 = __shfl(acc, base + 2);
    float a3 = __shfl(acc, base + 3);
    float h = a0 * W1[0 * R_N + rc] + a1 * W1[1 * R_N + rc]
            + a2 * W1[2 * R_N + rc] + a3 * W1[3 * R_N + rc];
    h1[((size_t)Bi * T_N + tb) * R_N + lane] = fmaxf(h, 0.f);
}

// pooled[B,r] = mean_t h1[B,t,r]; out[B,:] = softmax(pooled @ Wp). One wave per B.
__global__ void final_kernel(const float* __restrict__ h1, const float* __restrict__ Wp,
                             float* __restrict__ out) {
    int Bi = blockIdx.x;
    int lane = threadIdx.x;
    const float* hb = h1 + (size_t)Bi * T_N * R_N;
    float acc = 0.f;
    for (int k = lane; k < T_N * R_N; k += 64) acc += hb[k];   // k&3 == lane&3
    for (int m = 32; m >= 4; m >>= 1) acc += __shfl_xor(acc, m, 64);
    float pooled = acc * (1.0f / (float)T_N);   // every lane: pooled[lane&3]
    float q0 = __shfl(pooled, 0);
    float q1 = __shfl(pooled, 1);
    float q2 = __shfl(pooled, 2);
    float q3 = __shfl(pooled, 3);
    float logit = -INFINITY;
    if (lane < 8)
        logit = q0 * Wp[0 * S_N + lane] + q1 * Wp[1 * S_N + lane]
              + q2 * Wp[2 * S_N + lane] + q3 * Wp[3 * S_N + lane];
    float mx = logit;
    for (int m = 4; m >= 1; m >>= 1) mx = fmaxf(mx, __shfl_xor(mx, m, 8));
    float e = (lane < 8) ? __expf(logit - mx) : 0.f;
    float s = e;
    for (int m = 4; m >= 1; m >>= 1) s += __shfl_xor(s, m, 8);
    if (lane < 8) out[Bi * S_N + lane] = e / s;
}

extern "C" void kernel_launch(void* const* d_in, const int* in_sizes, int n_in,
                              void* d_out, int out_size, void* d_ws, size_t ws_size,
                              hipStream_t stream) {
    const float* x  = (const float*)d_in[0];   // [64,256,64]
    const float* W0 = (const float*)d_in[1];   // [64,4]
    const float* W1 = (const float*)d_in[2];   // [4,4]
    const float* Wp = (const float*)d_in[3];   // [4,8]
    float* out = (float*)d_out;                // [64,8]

    char* ws = (char*)d_ws;
    float* adj0 = (float*)(ws);                         // 4096 f = 16 KB
    float* h0   = (float*)(ws + 16384);                 // 65536 f = 256 KB
    float* adj1 = (float*)(ws + 16384 + 262144);        // 4096 f
    float* h1   = (float*)(ws + 16384 + 262144 + 16384);// 65536 f

    // Layer 0
    gram_kernel<<<1024, 256, 0, stream>>>(x, adj0, T_N * E_N);       // 4096 waves
    sparsemax_kernel<<<1, 64, 0, stream>>>(adj0);
    agg0_kernel<<<4096, 256, 0, stream>>>(x, adj0, W0, h0);          // 16384 waves
    // Layer 1
    gram_kernel<<<1024, 256, 0, stream>>>(h0, adj1, T_N * R_N);
    sparsemax_kernel<<<1, 64, 0, stream>>>(adj1);
    agg1_kernel<<<256, 256, 0, stream>>>(h0, adj1, W1, h1);          // 1024 waves
    // Head
    final_kernel<<<64, 64, 0, stream>>>(h1, Wp, out);
}

// Round 2
// 179.284 us; speedup vs baseline: 3.3612x; 3.3612x over previous
//
#include <hip/hip_runtime.h>
#include <math.h>

#define B_N 64
#define T_N 256
#define E_N 64
#define R_N 4
#define S_N 8

// adj[i,j] = dot(X[i,:], X[j,:]) / T ; X: [64, L]. One wave per (i,j) pair.
__global__ void gram_kernel(const float* __restrict__ X, float* __restrict__ adj, int L) {
    int wave = (blockIdx.x * blockDim.x + threadIdx.x) >> 6;
    int lane = threadIdx.x & 63;
    int i = wave >> 6;
    int j = wave & 63;
    const float* xi = X + (size_t)i * L;
    const float* xj = X + (size_t)j * L;
    float acc = 0.f;
    for (int k = lane; k < L; k += 64) acc += xi[k] * xj[k];
    for (int m = 32; m >= 1; m >>= 1) acc += __shfl_xor(acc, m, 64);
    if (lane == 0) adj[i * 64 + j] = acc * (1.0f / (float)T_N);
}

// Row-wise sparsemax on [64,64], in place. One WAVE per row; lane j holds elem j.
// Bitonic sort (descending) + shfl prefix-scan + ballot support count.
__global__ void sparsemax_kernel(float* adj) {
    int row = blockIdx.x * (blockDim.x >> 6) + (threadIdx.x >> 6);
    int lane = threadIdx.x & 63;
    float z = adj[row * 64 + lane];

    // bitonic sort, descending across 64 lanes
    float v = z;
    for (int k = 2; k <= 64; k <<= 1) {
        bool desc = (lane & k) == 0;   // final k=64 stage: all-descending
        for (int j = k >> 1; j > 0; j >>= 1) {
            float other = __shfl_xor(v, j, 64);
            bool lower = (lane & j) == 0;
            float mn = fminf(v, other), mx = fmaxf(v, other);
            v = (desc ^ lower) ? mn : mx;
        }
    }
    // inclusive prefix sum of sorted values
    float c = v;
    for (int d = 1; d < 64; d <<= 1) {
        float n = __shfl_up(c, d, 64);
        if (lane >= d) c += n;
    }
    // support count: sum over k of [1 + k*zs[k-1] > zcum[k-1]]
    bool sup = (1.0f + (float)(lane + 1) * v) > c;
    int ksel = __popcll(__ballot(sup));
    float zk = __shfl(c, ksel - 1, 64);
    float tau = (zk - 1.0f) / (float)ksel;
    adj[row * 64 + lane] = fmaxf(z - tau, 0.f);
}

// Layer-0: agg[B,t,e] = sum_b max_{b' in [b-1,b+2]} adj[B,b']*x[b',t,e]
// then h0[B,t,r] = relu(sum_e agg * W0[e,r]). One wave per (B,t); lane = e.
__global__ void agg0_kernel(const float* __restrict__ x, const float* __restrict__ adj,
                            const float* __restrict__ W0, float* __restrict__ h0) {
    int wave = (blockIdx.x * blockDim.x + threadIdx.x) >> 6;
    int lane = threadIdx.x & 63;
    int Bi = wave >> 8;        // / 256
    int t  = wave & 255;
    float p = adj[Bi * 64 + lane];              // lane holds adj[Bi, lane]
    const float* xb = x + (size_t)t * E_N + lane;   // x[(b*T + t)*E + lane]
    const size_t bs = (size_t)T_N * E_N;
    // sliding window over b: window for output b = {b-1, b, b+1, b+2}, -inf pad
    float vm1 = -INFINITY;
    float v0 = __shfl(p, 0) * xb[0];
    float v1 = __shfl(p, 1) * xb[bs];
    float acc = 0.f;
    for (int b = 0; b < 64; b++) {
        float v2 = (b + 2 < 64) ? __shfl(p, b + 2) * xb[(size_t)(b + 2) * bs] : -INFINITY;
        acc += fmaxf(fmaxf(vm1, v0), fmaxf(v1, v2));
        vm1 = v0; v0 = v1; v1 = v2;
    }
    // GEMM E->4 + relu via 4 butterfly reductions
    const float* wrow = W0 + lane * R_N;
    float p0 = acc * wrow[0], p1 = acc * wrow[1], p2 = acc * wrow[2], p3 = acc * wrow[3];
    for (int m = 32; m >= 1; m >>= 1) {
        p0 += __shfl_xor(p0, m, 64);
        p1 += __shfl_xor(p1, m, 64);
        p2 += __shfl_xor(p2, m, 64);
        p3 += __shfl_xor(p3, m, 64);
    }
    if (lane == 0) {
        float* o = h0 + ((size_t)Bi * T_N + t) * R_N;
        o[0] = fmaxf(p0, 0.f); o[1] = fmaxf(p1, 0.f);
        o[2] = fmaxf(p2, 0.f); o[3] = fmaxf(p3, 0.f);
    }
}

// Layer-1: same aggregation on h0 [64,256,4], then 4x4 GEMM + relu.
// One wave handles (B, 16 t's); lane = tl*4 + r (coalesced along flat [t,r]).
__global__ void agg1_kernel(const float* __restrict__ h0, const float* __restrict__ adj,
                            const float* __restrict__ W1, float* __restrict__ h1) {
    int wave = (blockIdx.x * blockDim.x + threadIdx.x) >> 6;
    int lane = threadIdx.x & 63;
    int Bi = wave >> 4;            // 64 B's
    int tb = (wave & 15) * 16;     // 16 t's per wave
    float p = adj[Bi * 64 + lane];
    const float* xb = h0 + (size_t)tb * R_N + lane;  // h0[(b*T + tb)*4 + lane]
    const size_t bs = (size_t)T_N * R_N;
    float vm1 = -INFINITY;
    float v0 = __shfl(p, 0) * xb[0];
    float v1 = __shfl(p, 1) * xb[bs];
    float acc = 0.f;
    for (int b = 0; b < 64; b++) {
        float v2 = (b + 2 < 64) ? __shfl(p, b + 2) * xb[(size_t)(b + 2) * bs] : -INFINITY;
        acc += fmaxf(fmaxf(vm1, v0), fmaxf(v1, v2));
        vm1 = v0; v0 = v1; v1 = v2;
    }
    // 4x4 GEMM within each quad of lanes
    int base = lane & ~3;
    int rc = lane & 3;
    float a0 = __shfl(acc, base + 0);
    float a1 = __shfl(acc, base + 1);
    float a2 = __shfl(acc, base + 2);
    float a3 = __shfl(acc, base + 3);
    float h = a0 * W1[0 * R_N + rc] + a1 * W1[1 * R_N + rc]
            + a2 * W1[2 * R_N + rc] + a3 * W1[3 * R_N + rc];
    h1[((size_t)Bi * T_N + tb) * R_N + lane] = fmaxf(h, 0.f);
}

// pooled[B,r] = mean_t h1[B,t,r]; out[B,:] = softmax(pooled @ Wp). One wave per B.
__global__ void final_kernel(const float* __restrict__ h1, const float* __restrict__ Wp,
                             float* __restrict__ out) {
    int Bi = blockIdx.x;
    int lane = threadIdx.x;
    const float* hb = h1 + (size_t)Bi * T_N * R_N;
    float acc = 0.f;
    for (int k = lane; k < T_N * R_N; k += 64) acc += hb[k];   // k&3 == lane&3
    for (int m = 32; m >= 4; m >>= 1) acc += __shfl_xor(acc, m, 64);
    float pooled = acc * (1.0f / (float)T_N);   // every lane: pooled[lane&3]
    float q0 = __shfl(pooled, 0);
    float q1 = __shfl(pooled, 1);
    float q2 = __shfl(pooled, 2);
    float q3 = __shfl(pooled, 3);
    float logit = -INFINITY;
    if (lane < 8)
        logit = q0 * Wp[0 * S_N + lane] + q1 * Wp[1 * S_N + lane]
              + q2 * Wp[2 * S_N + lane] + q3 * Wp[3 * S_N + lane];
    float mx = logit;
    for (int m = 4; m >= 1; m >>= 1) mx = fmaxf(mx, __shfl_xor(mx, m, 8));
    float e = (lane < 8) ? __expf(logit - mx) : 0.f;
    float s = e;
    for (int m = 4; m >= 1; m >>= 1) s += __shfl_xor(s, m, 8);
    if (lane < 8) out[Bi * S_N + lane] = e / s;
}

extern "C" void kernel_launch(void* const* d_in, const int* in_sizes, int n_in,
                              void* d_out, int out_size, void* d_ws, size_t ws_size,
                              hipStream_t stream) {
    const float* x  = (const float*)d_in[0];   // [64,256,64]
    const float* W0 = (const float*)d_in[1];   // [64,4]
    const float* W1 = (const float*)d_in[2];   // [4,4]
    const float* Wp = (const float*)d_in[3];   // [4,8]
    float* out = (float*)d_out;                // [64,8]

    char* ws = (char*)d_ws;
    float* adj0 = (float*)(ws);                         // 4096 f = 16 KB
    float* h0   = (float*)(ws + 16384);                 // 65536 f = 256 KB
    float* adj1 = (float*)(ws + 16384 + 262144);        // 4096 f
    float* h1   = (float*)(ws + 16384 + 262144 + 16384);// 65536 f

    // Layer 0
    gram_kernel<<<1024, 256, 0, stream>>>(x, adj0, T_N * E_N);       // 4096 waves
    sparsemax_kernel<<<16, 256, 0, stream>>>(adj0);                  // 64 waves, 1 row each
    agg0_kernel<<<4096, 256, 0, stream>>>(x, adj0, W0, h0);          // 16384 waves
    // Layer 1
    gram_kernel<<<1024, 256, 0, stream>>>(h0, adj1, T_N * R_N);
    sparsemax_kernel<<<16, 256, 0, stream>>>(adj1);
    agg1_kernel<<<256, 256, 0, stream>>>(h0, adj1, W1, h1);          // 1024 waves
    // Head
    final_kernel<<<64, 64, 0, stream>>>(h1, Wp, out);
}

// Round 3
// 118.981 us; speedup vs baseline: 5.0648x; 1.5068x over previous
//
#include <hip/hip_runtime.h>
#include <math.h>

#define B_N 64
#define T_N 256
#define E_N 64
#define R_N 4
#define S_N 8

__device__ __forceinline__ float4 f4max(float4 a, float4 b) {
    return make_float4(fmaxf(a.x, b.x), fmaxf(a.y, b.y), fmaxf(a.z, b.z), fmaxf(a.w, b.w));
}
__device__ __forceinline__ float4 f4scale(float s, float4 v) {
    return make_float4(s * v.x, s * v.y, s * v.z, s * v.w);
}
__device__ __forceinline__ float4 f4add(float4 a, float4 b) {
    return make_float4(a.x + b.x, a.y + b.y, a.z + b.z, a.w + b.w);
}
__device__ __forceinline__ float4 f4fma(float a, float4 b, float4 c) {
    return make_float4(fmaf(a, b.x, c.x), fmaf(a, b.y, c.y), fmaf(a, b.z, c.z), fmaf(a, b.w, c.w));
}

// ---------------------------------------------------------------------------
// gram_partial: P[c][i][j] = sum_{k in chunk c} X[i][k] X[j][k].
// One block per 64-wide K-chunk. X staged transposed in LDS (xsT[k][i]),
// each thread computes a 4x4 register tile with 2 ds_read_b128 per k.
// ---------------------------------------------------------------------------
__global__ void gram_partial(const float* __restrict__ X, float* __restrict__ P, int L) {
    __shared__ float xsT[64][68];   // pad 4: rows 16B-aligned, banks offset 4/row
    int tid = threadIdx.x;
    int k0 = blockIdx.x * 64;
    // stage: thread loads float4 along k, scatters 4 scalar LDS writes
#pragma unroll
    for (int it = 0; it < 4; ++it) {
        int f = it * 256 + tid;
        int i = f >> 4;             // 0..63
        int k4 = (f & 15) * 4;      // 0..60
        float4 v = *(const float4*)(X + (size_t)i * L + k0 + k4);
        xsT[k4 + 0][i] = v.x; xsT[k4 + 1][i] = v.y;
        xsT[k4 + 2][i] = v.z; xsT[k4 + 3][i] = v.w;
    }
    __syncthreads();
    int ti = (tid >> 4) * 4;        // i-tile base (0..60)
    int tj = (tid & 15) * 4;        // j-tile base (0..60)
    float4 acc0 = make_float4(0, 0, 0, 0), acc1 = acc0, acc2 = acc0, acc3 = acc0;
#pragma unroll 8
    for (int k = 0; k < 64; ++k) {
        float4 a = *(const float4*)&xsT[k][ti];   // 4 i's, one b128
        float4 b = *(const float4*)&xsT[k][tj];   // 4 j's, one b128
        acc0 = f4fma(a.x, b, acc0);
        acc1 = f4fma(a.y, b, acc1);
        acc2 = f4fma(a.z, b, acc2);
        acc3 = f4fma(a.w, b, acc3);
    }
    float* base = P + ((size_t)blockIdx.x << 12);
    *(float4*)(base + (ti + 0) * 64 + tj) = acc0;
    *(float4*)(base + (ti + 1) * 64 + tj) = acc1;
    *(float4*)(base + (ti + 2) * 64 + tj) = acc2;
    *(float4*)(base + (ti + 3) * 64 + tj) = acc3;
}

// ---------------------------------------------------------------------------
// reduce_sparsemax: adj[row][:] = sparsemax( scale * sum_c P[c][row][:] ).
// One block (4 waves) per row; wave-parallel partial sums, then wave 0 does
// the bitonic-sort sparsemax (verified in R2).
// ---------------------------------------------------------------------------
__global__ void reduce_sparsemax(const float* __restrict__ P, float* __restrict__ adj,
                                 int NC, float scale) {
    __shared__ float red[4][64];
    int tid = threadIdx.x;
    int row = blockIdx.x;
    int w = tid >> 6;
    int lane = tid & 63;
    int cpw = NC >> 2;
    float s = 0.f;
    for (int c = w * cpw; c < (w + 1) * cpw; ++c)
        s += P[((size_t)c << 12) + row * 64 + lane];
    red[w][lane] = s;
    __syncthreads();
    if (tid < 64) {
        float z = (red[0][lane] + red[1][lane] + red[2][lane] + red[3][lane]) * scale;
        // bitonic sort descending across 64 lanes
        float v = z;
        for (int k = 2; k <= 64; k <<= 1) {
            bool desc = (lane & k) == 0;
            for (int j = k >> 1; j > 0; j >>= 1) {
                float other = __shfl_xor(v, j, 64);
                bool lower = (lane & j) == 0;
                float mn = fminf(v, other), mx = fmaxf(v, other);
                v = (desc ^ lower) ? mn : mx;
            }
        }
        float c = v;
        for (int d = 1; d < 64; d <<= 1) {
            float n = __shfl_up(c, d, 64);
            if (lane >= d) c += n;
        }
        bool sup = (1.0f + (float)(lane + 1) * v) > c;
        int ksel = __popcll(__ballot(sup));
        float zk = __shfl(c, ksel - 1, 64);
        float tau = (zk - 1.0f) / (float)ksel;
        adj[row * 64 + lane] = fmaxf(z - tau, 0.f);
    }
}

// ---------------------------------------------------------------------------
// agg0: h0[B,t,r] = relu( sum_e [ sum_b max_{b' in [b-1,b+2]} adj[B,b']*x[b',t,e] ] * W0[e,r] )
// Block stages x[:, t0..t0+3, :] (64 KB LDS); each wave handles 2 B's;
// x read ONCE per b (b128) and reused; p via scalar loads (uniform).
// grid = 64 t-chunks x 8 B-chunks.
// ---------------------------------------------------------------------------
__global__ void agg0_kernel(const float* __restrict__ x, const float* __restrict__ adj,
                            const float* __restrict__ W0, float* __restrict__ h0) {
    __shared__ float xs[64 * 4 * 64];   // [b][tt][e] = 64 KB
    int tid = threadIdx.x;
    int t0 = (blockIdx.x >> 3) * 4;
    int Bc = (blockIdx.x & 7) * 8;
#pragma unroll
    for (int it = 0; it < 16; ++it) {
        int f = it * 256 + tid;
        int b = f >> 6;
        int tt = (f >> 4) & 3;
        int e4 = (f & 15) * 4;
        *(float4*)&xs[(b * 4 + tt) * 64 + e4] =
            *(const float4*)(x + ((size_t)(b * 256 + t0 + tt) * 64 + e4));
    }
    __syncthreads();
    int w = __builtin_amdgcn_readfirstlane(tid >> 6);   // wave id, provably uniform
    int lane = tid & 63;
    int t = lane >> 4;      // 0..3
    int eq = lane & 15;     // e-quad
    const float* pA = adj + (Bc + w * 2) * 64;          // scalar (uniform) base
    const float* pB = pA + 64;
    float4 w0r0 = *(const float4*)(W0 + (eq * 4 + 0) * 4);
    float4 w0r1 = *(const float4*)(W0 + (eq * 4 + 1) * 4);
    float4 w0r2 = *(const float4*)(W0 + (eq * 4 + 2) * 4);
    float4 w0r3 = *(const float4*)(W0 + (eq * 4 + 3) * 4);
    const float4* xsp = (const float4*)xs;
    const float4 NEG = make_float4(-INFINITY, -INFINITY, -INFINITY, -INFINITY);
    float4 accA = make_float4(0, 0, 0, 0), accB = accA;
    // v[b] = p[b]*x[b]; out[b] = max(v[b-1..b+2]); head: compute v[0], v[1]
    float4 x4 = xsp[(0 * 4 + t) * 16 + eq];
    float4 amA = NEG, a0A = f4scale(pA[0], x4), amB = NEG, a0B = f4scale(pB[0], x4);
    x4 = xsp[(1 * 4 + t) * 16 + eq];
    float4 a1A = f4scale(pA[1], x4), a1B = f4scale(pB[1], x4);
#pragma unroll 8
    for (int bl = 2; bl < 64; ++bl) {
        x4 = xsp[(bl * 4 + t) * 16 + eq];
        float4 v2A = f4scale(pA[bl], x4);
        float4 v2B = f4scale(pB[bl], x4);
        accA = f4add(accA, f4max(f4max(amA, a0A), f4max(a1A, v2A)));
        accB = f4add(accB, f4max(f4max(amB, a0B), f4max(a1B, v2B)));
        amA = a0A; a0A = a1A; a1A = v2A;
        amB = a0B; a0B = a1B; a1B = v2B;
    }
    // tails: out[62] (window 61,62,63,-inf), out[63] (62,63,-inf,-inf)
    accA = f4add(accA, f4max(f4max(amA, a0A), a1A));
    accB = f4add(accB, f4max(f4max(amB, a0B), a1B));
    accA = f4add(accA, f4max(a0A, a1A));
    accB = f4add(accB, f4max(a0B, a1B));
    // project E->4 and reduce across the 16 eq-lanes of this t
#pragma unroll
    for (int half = 0; half < 2; ++half) {
        float4 acc = half ? accB : accA;
        int B = Bc + w * 2 + half;
        float4 h = f4fma(acc.x, w0r0, f4fma(acc.y, w0r1,
                   f4fma(acc.z, w0r2, f4scale(acc.w, w0r3))));
        for (int m = 1; m <= 8; m <<= 1) {
            h.x += __shfl_xor(h.x, m, 64);
            h.y += __shfl_xor(h.y, m, 64);
            h.z += __shfl_xor(h.z, m, 64);
            h.w += __shfl_xor(h.w, m, 64);
        }
        if (eq == 0) {
            float4 r = make_float4(fmaxf(h.x, 0.f), fmaxf(h.y, 0.f),
                                   fmaxf(h.z, 0.f), fmaxf(h.w, 0.f));
            *(float4*)(h0 + (size_t)(B * 256 + t0 + t) * 4) = r;
        }
    }
}

// ---------------------------------------------------------------------------
// agg1: same aggregation on h0 [64,256,4] + 4x4 GEMM + relu.
// Bi uniform from blockIdx -> p loads scalarize (no bpermute in loop).
// grid = 256 blocks (64 B x 4 t-quads), 4 waves each handling 16 t's.
// ---------------------------------------------------------------------------
__global__ void agg1_kernel(const float* __restrict__ h0, const float* __restrict__ adj,
                            const float* __restrict__ W1, float* __restrict__ h1) {
    int tid = threadIdx.x;
    int Bi = blockIdx.x >> 2;
    int w = __builtin_amdgcn_readfirstlane(tid >> 6);
    int tb = ((blockIdx.x & 3) * 4 + w) * 16;
    int lane = tid & 63;
    const float* prow = adj + Bi * 64;                 // uniform base
    const float* xb = h0 + (size_t)tb * 4 + lane;      // stride 1024 floats per b
    float acc = 0.f;
    float am = -INFINITY;
    float a0 = prow[0] * xb[0];
    float a1 = prow[1] * xb[1024];
#pragma unroll 8
    for (int bl = 2; bl < 64; ++bl) {
        float v2 = prow[bl] * xb[(size_t)bl * 1024];
        acc += fmaxf(fmaxf(am, a0), fmaxf(a1, v2));
        am = a0; a0 = a1; a1 = v2;
    }
    acc += fmaxf(fmaxf(am, a0), a1);
    acc += fmaxf(a0, a1);
    int base = lane & ~3;
    int rc = lane & 3;
    float b0 = __shfl(acc, base + 0, 64);
    float b1 = __shfl(acc, base + 1, 64);
    float b2 = __shfl(acc, base + 2, 64);
    float b3 = __shfl(acc, base + 3, 64);
    float h = b0 * W1[0 * 4 + rc] + b1 * W1[1 * 4 + rc]
            + b2 * W1[2 * 4 + rc] + b3 * W1[3 * 4 + rc];
    h1[(size_t)(Bi * 256 + tb) * 4 + lane] = fmaxf(h, 0.f);
}

// ---------------------------------------------------------------------------
// final: pooled = mean_t h1; out = softmax(pooled @ Wp). One wave per B.
// ---------------------------------------------------------------------------
__global__ void final_kernel(const float* __restrict__ h1, const float* __restrict__ Wp,
                             float* __restrict__ out) {
    int Bi = blockIdx.x;
    int lane = threadIdx.x;
    const float* hb = h1 + (size_t)Bi * T_N * R_N;
    float acc = 0.f;
    for (int k = lane; k < T_N * R_N; k += 64) acc += hb[k];
    for (int m = 32; m >= 4; m >>= 1) acc += __shfl_xor(acc, m, 64);
    float pooled = acc * (1.0f / (float)T_N);
    float q0 = __shfl(pooled, 0, 64);
    float q1 = __shfl(pooled, 1, 64);
    float q2 = __shfl(pooled, 2, 64);
    float q3 = __shfl(pooled, 3, 64);
    float logit = -INFINITY;
    if (lane < 8)
        logit = q0 * Wp[0 * S_N + lane] + q1 * Wp[1 * S_N + lane]
              + q2 * Wp[2 * S_N + lane] + q3 * Wp[3 * S_N + lane];
    float mx = logit;
    for (int m = 4; m >= 1; m >>= 1) mx = fmaxf(mx, __shfl_xor(mx, m, 8));
    float e = (lane < 8) ? __expf(logit - mx) : 0.f;
    float s = e;
    for (int m = 4; m >= 1; m >>= 1) s += __shfl_xor(s, m, 8);
    if (lane < 8) out[Bi * S_N + lane] = e / s;
}

extern "C" void kernel_launch(void* const* d_in, const int* in_sizes, int n_in,
                              void* d_out, int out_size, void* d_ws, size_t ws_size,
                              hipStream_t stream) {
    const float* x  = (const float*)d_in[0];   // [64,256,64]
    const float* W0 = (const float*)d_in[1];   // [64,4]
    const float* W1 = (const float*)d_in[2];   // [4,4]
    const float* Wp = (const float*)d_in[3];   // [4,8]
    float* out = (float*)d_out;                // [64,8]

    char* ws = (char*)d_ws;
    float* P    = (float*)(ws);                              // 256*16KB = 4 MB
    float* adj0 = (float*)(ws + 4194304);                    // 16 KB
    float* h0   = (float*)(ws + 4194304 + 16384);            // 256 KB
    float* adj1 = (float*)(ws + 4194304 + 16384 + 262144);   // 16 KB
    float* h1   = (float*)(ws + 4194304 + 2 * 16384 + 262144); // 256 KB

    const float invT = 1.0f / (float)T_N;
    // Layer 0
    gram_partial<<<256, 256, 0, stream>>>(x, P, T_N * E_N);
    reduce_sparsemax<<<64, 256, 0, stream>>>(P, adj0, 256, invT);
    agg0_kernel<<<512, 256, 0, stream>>>(x, adj0, W0, h0);
    // Layer 1
    gram_partial<<<16, 256, 0, stream>>>(h0, P, T_N * R_N);
    reduce_sparsemax<<<64, 256, 0, stream>>>(P, adj1, 16, invT);
    agg1_kernel<<<256, 256, 0, stream>>>(h0, adj1, W1, h1);
    // Head
    final_kernel<<<64, 64, 0, stream>>>(h1, Wp, out);
}